// Round 7
// baseline (1333.771 us; speedup 1.0000x reference)
//
#include <hip/hip_runtime.h>
#include <math.h>

#define NEG_SLOPE 0.2f
#define BN_EPS 1e-5f
#define BSHIFT 7
#define BSIZE 128          // nodes per bucket
#define NBMAX 512          // max buckets supported (n <= 65536)
#define BIN_CHUNK 8192

static __device__ __forceinline__ float wave_red_sum(float v) {
    for (int off = 32; off; off >>= 1) v += __shfl_xor(v, off);
    return v;
}

// fp32 -> bf16 bits, round-to-nearest-even
static __device__ __forceinline__ unsigned short f2bf(float f) {
    unsigned int u = __float_as_uint(f);
    unsigned int r = u + 0x7FFFu + ((u >> 16) & 1u);
    return (unsigned short)(r >> 16);
}

static __device__ __forceinline__ unsigned int pack2(float a, float b) {
    return (unsigned int)f2bf(a) | ((unsigned int)f2bf(b) << 16);
}

// ---------------- binned CSR build ----------------
__global__ void k_zero(int* p, int m) {
    int i = blockIdx.x * blockDim.x + threadIdx.x;
    if (i < m) p[i] = 0;
}

__global__ void __launch_bounds__(256) k_bucket_count(const int* __restrict__ dst, int E4,
                                                      int* __restrict__ bcnt) {
    __shared__ int lc[NBMAX];
    for (int i = threadIdx.x; i < NBMAX; i += 256) lc[i] = 0;
    __syncthreads();
    const int4* d4 = (const int4*)dst;
    int stride = gridDim.x * blockDim.x;
    for (int i = blockIdx.x * blockDim.x + threadIdx.x; i < E4; i += stride) {
        int4 v = d4[i];
        atomicAdd(&lc[v.x >> BSHIFT], 1);
        atomicAdd(&lc[v.y >> BSHIFT], 1);
        atomicAdd(&lc[v.z >> BSHIFT], 1);
        atomicAdd(&lc[v.w >> BSHIFT], 1);
    }
    __syncthreads();
    for (int i = threadIdx.x; i < NBMAX; i += 256)
        if (lc[i] > 0) atomicAdd(&bcnt[i], lc[i]);
}

__global__ void __launch_bounds__(256) k_bucket_scan(const int* __restrict__ bcnt, int NB,
                                                     int* __restrict__ bstart,
                                                     int* __restrict__ gcursor) {
    __shared__ int wsum[256];
    int tid = threadIdx.x;
    int i0 = tid * 2, i1 = tid * 2 + 1;
    int v0 = bcnt[i0], v1 = bcnt[i1];
    int s = v0 + v1;
    wsum[tid] = s;
    __syncthreads();
    for (int off = 1; off < 256; off <<= 1) {
        int t = (tid >= off) ? wsum[tid - off] : 0;
        __syncthreads();
        wsum[tid] += t;
        __syncthreads();
    }
    int excl = wsum[tid] - s;
    if (i0 < NB) { bstart[i0] = excl; gcursor[i0] = excl; }
    excl += v0;
    if (i1 < NB) { bstart[i1] = excl; gcursor[i1] = excl; }
    if (tid == 255) bstart[NB] = wsum[255];
}

__global__ void __launch_bounds__(256) k_bin(const int* __restrict__ src,
                                             const int* __restrict__ dst, int E,
                                             int* __restrict__ gcursor,
                                             int2* __restrict__ binned) {
    __shared__ int lc[NBMAX], lbase[NBMAX];
    int e0 = blockIdx.x * BIN_CHUNK;
    int e1 = min(e0 + BIN_CHUNK, E);
    for (int i = threadIdx.x; i < NBMAX; i += 256) lc[i] = 0;
    __syncthreads();
    for (int i = e0 + threadIdx.x; i < e1; i += 256)
        atomicAdd(&lc[dst[i] >> BSHIFT], 1);
    __syncthreads();
    for (int i = threadIdx.x; i < NBMAX; i += 256) {
        int c = lc[i];
        if (c > 0) lbase[i] = atomicAdd(&gcursor[i], c);
    }
    __syncthreads();
    for (int i = threadIdx.x; i < NBMAX; i += 256) lc[i] = 0;
    __syncthreads();
    for (int i = e0 + threadIdx.x; i < e1; i += 256) {
        int d = dst[i];
        int b = d >> BSHIFT;
        int pos = lbase[b] + atomicAdd(&lc[b], 1);
        binned[pos] = make_int2(src[i], d);
    }
}

__global__ void __launch_bounds__(256) k_bucket_csr(
    const int2* __restrict__ binned, const int* __restrict__ bstart, int n, int NB,
    int* __restrict__ row_ptr, int* __restrict__ csr_src) {
    __shared__ int cnt[BSIZE];
    __shared__ int wsum[BSIZE];
    int b = blockIdx.x;
    int node0 = b << BSHIFT;
    int nnodes = min(BSIZE, n - node0);
    int tid = threadIdx.x;
    if (tid < BSIZE) cnt[tid] = (tid < nnodes) ? 1 : 0;  // self loop
    __syncthreads();
    int ebeg = bstart[b], eend = bstart[b + 1];
    for (int i = ebeg + tid; i < eend; i += 256)
        atomicAdd(&cnt[binned[i].y & (BSIZE - 1)], 1);
    __syncthreads();
    int c = 0;
    if (tid < BSIZE) { c = cnt[tid]; wsum[tid] = c; }
    __syncthreads();
    for (int off = 1; off < BSIZE; off <<= 1) {
        int t = (tid >= off && tid < BSIZE) ? wsum[tid - off] : 0;
        __syncthreads();
        if (tid < BSIZE) wsum[tid] += t;
        __syncthreads();
    }
    int csr_base = ebeg + node0;
    if (tid < BSIZE) {
        int excl = wsum[tid] - c;
        int node = node0 + tid;
        if (tid < nnodes) {
            row_ptr[node] = csr_base + excl;
            csr_src[csr_base + excl] = node;  // self loop first
        }
        cnt[tid] = excl + 1;
    }
    if (b == NB - 1 && tid == BSIZE - 1) row_ptr[n] = csr_base + wsum[BSIZE - 1];
    __syncthreads();
    for (int i = ebeg + tid; i < eend; i += 256) {
        int2 e2 = binned[i];
        int pos = csr_base + atomicAdd(&cnt[e2.y & (BSIZE - 1)], 1);
        csr_src[pos] = e2.x;
    }
}

// ---------------- node-per-lane GEMM: H(bf16) = act(X) @ W, fused scores ----------------
// Block = 128 threads = 128 nodes; thread owns acc[64] (full output row) in VGPRs.
// X staged transposed into LDS as float4 k-groups: Xt[c][node] covers features
// p*64 + c*4 .. +3. W slab staged in LDS, read broadcast float4 (1 read : 4 FMA).
// FIN=128 runs as two 64-k phases reusing the same LDS. No shuffles anywhere.
template <int FIN, int USE_BN>
__global__ void __launch_bounds__(128) k_gemm(
    const float* __restrict__ X, const float* __restrict__ W,
    const float* __restrict__ a_src, const float* __restrict__ a_dst,
    const float* __restrict__ bn_sc, const float* __restrict__ bn_sh,
    unsigned short* __restrict__ H16, float* __restrict__ S, float* __restrict__ Dv, int n) {
    constexpr int RF4 = FIN / 4;
    __shared__ float4 Xt[16][128];   // 32 KB: [k-group within slab][node]
    __shared__ float4 Wl[64 * 16];   // 16 KB: [k within slab][f-group]
    const int node0 = blockIdx.x * 128;
    const int t = threadIdx.x;
    const int node = node0 + t;

    float acc[64];
    #pragma unroll
    for (int f = 0; f < 64; f++) acc[f] = 0.f;

    const float4* X4 = (const float4*)X;
    const float4* W4 = (const float4*)W;

    #pragma unroll
    for (int p = 0; p < FIN / 64; ++p) {
        if (p) __syncthreads();
        // stage W slab (rows p*64 .. p*64+63): 1024 float4, coalesced, linear LDS
        #pragma unroll
        for (int i = 0; i < 8; i++) {
            int idx = i * 128 + t;
            Wl[idx] = W4[p * 1024 + idx];
        }
        // stage X slab transposed: c = t%16 (k-group), r = i*8 + t/16 (node)
        #pragma unroll
        for (int i = 0; i < 16; i++) {
            int c = t & 15;
            int r = i * 8 + (t >> 4);
            float4 v = make_float4(0.f, 0.f, 0.f, 0.f);
            if (node0 + r < n) v = X4[(size_t)(node0 + r) * RF4 + p * 16 + c];
            if (USE_BN) {
                int kb = p * 64 + c * 4;
                v.x = fmaxf(fmaf(v.x, bn_sc[kb + 0], bn_sh[kb + 0]), 0.f);
                v.y = fmaxf(fmaf(v.y, bn_sc[kb + 1], bn_sh[kb + 1]), 0.f);
                v.z = fmaxf(fmaf(v.z, bn_sc[kb + 2], bn_sh[kb + 2]), 0.f);
                v.w = fmaxf(fmaf(v.w, bn_sc[kb + 3], bn_sh[kb + 3]), 0.f);
            }
            Xt[c][r] = v;
        }
        __syncthreads();
        // compute: per k-group one conflict-free b128 X read; W broadcast b128
        #pragma unroll
        for (int c = 0; c < 16; c++) {
            float4 xv = Xt[c][t];
            #pragma unroll
            for (int j = 0; j < 4; j++) {
                float xs = (j == 0) ? xv.x : (j == 1) ? xv.y : (j == 2) ? xv.z : xv.w;
                #pragma unroll
                for (int fg = 0; fg < 16; fg++) {
                    float4 wv = Wl[(c * 4 + j) * 16 + fg];
                    acc[fg * 4 + 0] = fmaf(xs, wv.x, acc[fg * 4 + 0]);
                    acc[fg * 4 + 1] = fmaf(xs, wv.y, acc[fg * 4 + 1]);
                    acc[fg * 4 + 2] = fmaf(xs, wv.z, acc[fg * 4 + 2]);
                    acc[fg * 4 + 3] = fmaf(xs, wv.w, acc[fg * 4 + 3]);
                }
            }
        }
    }

    if (node < n) {
        // H row: pack bf16 pairs, 8 x dwordx4 stores (128B contiguous per lane)
        uint4* Hrow = (uint4*)(H16 + (size_t)node * 64);
        #pragma unroll
        for (int q = 0; q < 8; q++) {
            uint4 u;
            u.x = pack2(acc[q * 8 + 0], acc[q * 8 + 1]);
            u.y = pack2(acc[q * 8 + 2], acc[q * 8 + 3]);
            u.z = pack2(acc[q * 8 + 4], acc[q * 8 + 5]);
            u.w = pack2(acc[q * 8 + 6], acc[q * 8 + 7]);
            Hrow[q] = u;
        }
        // per-lane serial score dots (uniform a_src/a_dst reads)
        float s = 0.f, d = 0.f;
        #pragma unroll
        for (int f = 0; f < 64; f++) {
            s = fmaf(acc[f], a_src[f], s);
            d = fmaf(acc[f], a_dst[f], d);
        }
        S[node] = s;
        Dv[node] = d;
    }
}

// ---------------- node-parallel GAT aggregate (bf16 H gather) ----------------
__global__ void __launch_bounds__(256) k_aggregate(
    const unsigned int* __restrict__ H2, const float* __restrict__ S,
    const float* __restrict__ Dv,
    const int* __restrict__ row_ptr, const int* __restrict__ csr_src,
    const float* __restrict__ bias, float* __restrict__ out, int n) {
    int wave = threadIdx.x >> 6, lane = threadIdx.x & 63;
    int node = blockIdx.x * 4 + wave;
    if (node >= n) return;
    int start = row_ptr[node], end = row_ptr[node + 1];
    float dn = Dv[node];
    int half = lane >> 5;
    int col = lane & 31;
    float accL0 = 0.f, accH0 = 0.f, accL1 = 0.f, accH1 = 0.f;
    float zlane = 0.f;
    for (int base = start; base < end; base += 64) {
        int cnt = min(64, end - base);
        int sj = 0;
        float w = 0.f;
        if (lane < cnt) {
            sj = csr_src[base + lane];
            float t = S[sj] + dn;
            t = (t > 0.f) ? t : NEG_SLOPE * t;
            w = __expf(t);
        }
        zlane += w;
        for (int jj = 0; jj < cnt; jj += 4) {
            int i0 = min(jj + half, 63);
            int i1 = min(jj + 2 + half, 63);
            float w0 = __shfl(w, i0);
            float w1 = __shfl(w, i1);
            int s0 = __shfl(sj, i0);
            int s1 = __shfl(sj, i1);
            unsigned int u0 = H2[(size_t)s0 * 32 + col];
            unsigned int u1 = H2[(size_t)s1 * 32 + col];
            float l0 = __uint_as_float(u0 << 16);
            float h0 = __uint_as_float(u0 & 0xFFFF0000u);
            float l1 = __uint_as_float(u1 << 16);
            float h1 = __uint_as_float(u1 & 0xFFFF0000u);
            accL0 = fmaf(w0, l0, accL0);
            accH0 = fmaf(w0, h0, accH0);
            accL1 = fmaf(w1, l1, accL1);
            accH1 = fmaf(w1, h1, accH1);
        }
    }
    float z = wave_red_sum(zlane);
    float accL = accL0 + accL1;
    float accH = accH0 + accH1;
    accL += __shfl_xor(accL, 32);
    accH += __shfl_xor(accH, 32);
    if (half == 0) {
        float2 b2 = ((const float2*)bias)[col];
        float2 o;
        o.x = accL / z + b2.x;
        o.y = accH / z + b2.y;
        ((float2*)out)[(size_t)node * 32 + col] = o;
    }
}

// ---------------- batchnorm stats ----------------
__global__ void k_zero_stats(float* stats) {
    if (threadIdx.x < 128) stats[threadIdx.x] = 0.f;
}

__global__ void __launch_bounds__(256) k_colstats(const float* __restrict__ T, int n,
                                                  float* __restrict__ sums,
                                                  float* __restrict__ sumsq) {
    __shared__ float ls[256], lq[256];
    int f = threadIdx.x & 63;
    int rowgrp = threadIdx.x >> 6;
    float s = 0.f, q = 0.f;
    for (int r = blockIdx.x * 4 + rowgrp; r < n; r += gridDim.x * 4) {
        float v = T[(size_t)r * 64 + f];
        s += v;
        q += v * v;
    }
    ls[threadIdx.x] = s; lq[threadIdx.x] = q;
    __syncthreads();
    if (threadIdx.x < 128) {
        ls[threadIdx.x] += ls[threadIdx.x + 128];
        lq[threadIdx.x] += lq[threadIdx.x + 128];
    }
    __syncthreads();
    if (threadIdx.x < 64) {
        atomicAdd(&sums[f], ls[threadIdx.x] + ls[threadIdx.x + 64]);
        atomicAdd(&sumsq[f], lq[threadIdx.x] + lq[threadIdx.x + 64]);
    }
}

__global__ void k_bn_finalize(const float* __restrict__ sums, const float* __restrict__ sumsq,
                              const float* __restrict__ g, const float* __restrict__ be,
                              int n, float* __restrict__ sc, float* __restrict__ sh) {
    int f = threadIdx.x;
    if (f < 64) {
        float inv_n = 1.f / (float)n;
        float mu = sums[f] * inv_n;
        float var = sumsq[f] * inv_n - mu * mu;
        float rstd = rsqrtf(var + BN_EPS);
        float scale = rstd * g[f];
        sc[f] = scale;
        sh[f] = be[f] - mu * scale;
    }
}

extern "C" void kernel_launch(void* const* d_in, const int* in_sizes, int n_in,
                              void* d_out, int out_size, void* d_ws, size_t ws_size,
                              hipStream_t stream) {
    const float* x        = (const float*)d_in[0];
    const int*   ei       = (const int*)d_in[1];
    const float* W_in     = (const float*)d_in[2];
    const float* a_src_in = (const float*)d_in[3];
    const float* a_dst_in = (const float*)d_in[4];
    const float* b_in     = (const float*)d_in[5];
    const float* W_mid    = (const float*)d_in[6];
    const float* a_src_mid= (const float*)d_in[7];
    const float* a_dst_mid= (const float*)d_in[8];
    const float* b_mid    = (const float*)d_in[9];
    const float* gamma    = (const float*)d_in[10];
    const float* beta     = (const float*)d_in[11];
    const float* W_out    = (const float*)d_in[12];
    const float* a_src_out= (const float*)d_in[13];
    const float* a_dst_out= (const float*)d_in[14];
    const float* b_out    = (const float*)d_in[15];

    int n = in_sizes[0] / 128;   // 50000
    int E = in_sizes[1] / 2;     // 1250000
    const int* srcE = ei;
    const int* dstE = ei + E;
    int NB = (n + BSIZE - 1) >> BSHIFT;   // 391 (<= NBMAX assumed)

    auto alignup = [](size_t v) { return (v + 255) & ~(size_t)255; };
    char* p = (char*)d_ws;
    int* bcnt    = (int*)p; p += alignup(NBMAX * 4);
    int* bstart  = (int*)p; p += alignup((NBMAX + 1) * 4);
    int* gcursor = (int*)p; p += alignup(NBMAX * 4);
    int* row_ptr = (int*)p; p += alignup((size_t)(n + 1) * 4);
    int2* binned = (int2*)p; p += alignup((size_t)E * 8);
    int* csr     = (int*)p; p += alignup((size_t)(E + n) * 4);
    unsigned int* H2 = (unsigned int*)p; p += alignup((size_t)n * 32 * 4);  // bf16 [n][64]
    float* S     = (float*)p; p += alignup((size_t)n * 4);
    float* Dv    = (float*)p; p += alignup((size_t)n * 4);
    float* stats = (float*)p; p += alignup(128 * 4);
    float* bnsc  = (float*)p; p += alignup(64 * 4);
    float* bnsh  = (float*)p; p += alignup(64 * 4);
    float* T     = (float*)d_out;  // layer ping buffer; final aggregate rewrites it
    unsigned short* H16 = (unsigned short*)H2;

    // ---- binned CSR build (edges identical across all 5 layers) ----
    k_zero<<<(NBMAX + 255) / 256, 256, 0, stream>>>(bcnt, NBMAX);
    k_bucket_count<<<256, 256, 0, stream>>>(dstE, E / 4, bcnt);
    k_bucket_scan<<<1, 256, 0, stream>>>(bcnt, NB, bstart, gcursor);
    k_bin<<<(E + BIN_CHUNK - 1) / BIN_CHUNK, 256, 0, stream>>>(srcE, dstE, E, gcursor, binned);
    k_bucket_csr<<<NB, 256, 0, stream>>>(binned, bstart, n, NB, row_ptr, csr);

    int gb = (n + 3) / 4;          // aggregate grid (4 nodes/block)
    int gg = (n + 127) / 128;      // gemm grid (128 nodes/block)

    // ---- input GAT layer ----
    k_gemm<128, 0><<<gg, 128, 0, stream>>>(x, W_in, a_src_in, a_dst_in, nullptr, nullptr,
                                           H16, S, Dv, n);
    k_aggregate<<<gb, 256, 0, stream>>>(H2, S, Dv, row_ptr, csr, b_in, T, n);

    // ---- mid layers: gat -> BN stats; BN+ReLU fused into next gemm's input ----
    for (int l = 0; l < 3; l++) {
        if (l == 0)
            k_gemm<64, 0><<<gg, 128, 0, stream>>>(T, W_mid + l * 4096, a_src_mid + l * 64,
                                                  a_dst_mid + l * 64, nullptr, nullptr,
                                                  H16, S, Dv, n);
        else
            k_gemm<64, 1><<<gg, 128, 0, stream>>>(T, W_mid + l * 4096, a_src_mid + l * 64,
                                                  a_dst_mid + l * 64, bnsc, bnsh,
                                                  H16, S, Dv, n);
        k_aggregate<<<gb, 256, 0, stream>>>(H2, S, Dv, row_ptr, csr, b_mid + l * 64, T, n);
        k_zero_stats<<<1, 128, 0, stream>>>(stats);
        k_colstats<<<512, 256, 0, stream>>>(T, n, stats, stats + 64);
        k_bn_finalize<<<1, 64, 0, stream>>>(stats, stats + 64, gamma + l * 64, beta + l * 64,
                                            n, bnsc, bnsh);
    }

    // ---- output GAT layer (consumes BN+ReLU of last mid layer) ----
    k_gemm<64, 1><<<gg, 128, 0, stream>>>(T, W_out, a_src_out, a_dst_out, bnsc, bnsh,
                                          H16, S, Dv, n);
    k_aggregate<<<gb, 256, 0, stream>>>(H2, S, Dv, row_ptr, csr, b_out, (float*)d_out, n);
}

// Round 8
// 563.749 us; speedup vs baseline: 2.3659x; 2.3659x over previous
//
#include <hip/hip_runtime.h>
#include <math.h>

#define NEG_SLOPE 0.2f
#define BN_EPS 1e-5f
#define BSHIFT 7
#define BSIZE 128          // nodes per bucket
#define NBMAX 512          // max buckets supported (n <= 65536)
#define BIN_CHUNK 8192

static __device__ __forceinline__ float wave_red_sum(float v) {
    for (int off = 32; off; off >>= 1) v += __shfl_xor(v, off);
    return v;
}

// fp32 -> bf16 bits, round-to-nearest-even
static __device__ __forceinline__ unsigned short f2bf(float f) {
    unsigned int u = __float_as_uint(f);
    unsigned int r = u + 0x7FFFu + ((u >> 16) & 1u);
    return (unsigned short)(r >> 16);
}

// ---------------- binned CSR build ----------------
__global__ void k_zero(int* p, int m) {
    int i = blockIdx.x * blockDim.x + threadIdx.x;
    if (i < m) p[i] = 0;
}

__global__ void __launch_bounds__(256) k_bucket_count(const int* __restrict__ dst, int E4,
                                                      int* __restrict__ bcnt) {
    __shared__ int lc[NBMAX];
    for (int i = threadIdx.x; i < NBMAX; i += 256) lc[i] = 0;
    __syncthreads();
    const int4* d4 = (const int4*)dst;
    int stride = gridDim.x * blockDim.x;
    for (int i = blockIdx.x * blockDim.x + threadIdx.x; i < E4; i += stride) {
        int4 v = d4[i];
        atomicAdd(&lc[v.x >> BSHIFT], 1);
        atomicAdd(&lc[v.y >> BSHIFT], 1);
        atomicAdd(&lc[v.z >> BSHIFT], 1);
        atomicAdd(&lc[v.w >> BSHIFT], 1);
    }
    __syncthreads();
    for (int i = threadIdx.x; i < NBMAX; i += 256)
        if (lc[i] > 0) atomicAdd(&bcnt[i], lc[i]);
}

__global__ void __launch_bounds__(256) k_bucket_scan(const int* __restrict__ bcnt, int NB,
                                                     int* __restrict__ bstart,
                                                     int* __restrict__ gcursor) {
    __shared__ int wsum[256];
    int tid = threadIdx.x;
    int i0 = tid * 2, i1 = tid * 2 + 1;
    int v0 = bcnt[i0], v1 = bcnt[i1];
    int s = v0 + v1;
    wsum[tid] = s;
    __syncthreads();
    for (int off = 1; off < 256; off <<= 1) {
        int t = (tid >= off) ? wsum[tid - off] : 0;
        __syncthreads();
        wsum[tid] += t;
        __syncthreads();
    }
    int excl = wsum[tid] - s;
    if (i0 < NB) { bstart[i0] = excl; gcursor[i0] = excl; }
    excl += v0;
    if (i1 < NB) { bstart[i1] = excl; gcursor[i1] = excl; }
    if (tid == 255) bstart[NB] = wsum[255];
}

__global__ void __launch_bounds__(256) k_bin(const int* __restrict__ src,
                                             const int* __restrict__ dst, int E,
                                             int* __restrict__ gcursor,
                                             int2* __restrict__ binned) {
    __shared__ int lc[NBMAX], lbase[NBMAX];
    int e0 = blockIdx.x * BIN_CHUNK;
    int e1 = min(e0 + BIN_CHUNK, E);
    for (int i = threadIdx.x; i < NBMAX; i += 256) lc[i] = 0;
    __syncthreads();
    for (int i = e0 + threadIdx.x; i < e1; i += 256)
        atomicAdd(&lc[dst[i] >> BSHIFT], 1);
    __syncthreads();
    for (int i = threadIdx.x; i < NBMAX; i += 256) {
        int c = lc[i];
        if (c > 0) lbase[i] = atomicAdd(&gcursor[i], c);
    }
    __syncthreads();
    for (int i = threadIdx.x; i < NBMAX; i += 256) lc[i] = 0;
    __syncthreads();
    for (int i = e0 + threadIdx.x; i < e1; i += 256) {
        int d = dst[i];
        int b = d >> BSHIFT;
        int pos = lbase[b] + atomicAdd(&lc[b], 1);
        binned[pos] = make_int2(src[i], d);
    }
}

__global__ void __launch_bounds__(256) k_bucket_csr(
    const int2* __restrict__ binned, const int* __restrict__ bstart, int n, int NB,
    int* __restrict__ row_ptr, int* __restrict__ csr_src) {
    __shared__ int cnt[BSIZE];
    __shared__ int wsum[BSIZE];
    int b = blockIdx.x;
    int node0 = b << BSHIFT;
    int nnodes = min(BSIZE, n - node0);
    int tid = threadIdx.x;
    if (tid < BSIZE) cnt[tid] = (tid < nnodes) ? 1 : 0;  // self loop
    __syncthreads();
    int ebeg = bstart[b], eend = bstart[b + 1];
    for (int i = ebeg + tid; i < eend; i += 256)
        atomicAdd(&cnt[binned[i].y & (BSIZE - 1)], 1);
    __syncthreads();
    int c = 0;
    if (tid < BSIZE) { c = cnt[tid]; wsum[tid] = c; }
    __syncthreads();
    for (int off = 1; off < BSIZE; off <<= 1) {
        int t = (tid >= off && tid < BSIZE) ? wsum[tid - off] : 0;
        __syncthreads();
        if (tid < BSIZE) wsum[tid] += t;
        __syncthreads();
    }
    int csr_base = ebeg + node0;
    if (tid < BSIZE) {
        int excl = wsum[tid] - c;
        int node = node0 + tid;
        if (tid < nnodes) {
            row_ptr[node] = csr_base + excl;
            csr_src[csr_base + excl] = node;  // self loop first
        }
        cnt[tid] = excl + 1;
    }
    if (b == NB - 1 && tid == BSIZE - 1) row_ptr[n] = csr_base + wsum[BSIZE - 1];
    __syncthreads();
    for (int i = ebeg + tid; i < eend; i += 256) {
        int2 e2 = binned[i];
        int pos = csr_base + atomicAdd(&cnt[e2.y & (BSIZE - 1)], 1);
        csr_src[pos] = e2.x;
    }
}

// ---------------- tiled per-layer GEMM: H(bf16) = X @ W, fused scores ----------------
// Round-6 shape (known-good: VGPR ~88): block = 64 nodes, 4 waves; wave computes
// 16 nodes x 64 features, lane = out feature, acc[16].
// CHANGE: X tile is consumed only by its owning wave and each element read once
// -> no X LDS staging; read X float4 directly from global (wave-uniform
// broadcast loads, L3-resident). Only W is staged in LDS (16/32 KB), lifting
// occupancy from 2 to ~4-5 blocks/CU. BN+ReLU moved to k_bn_apply (separate).
template <int FIN>
__global__ void __launch_bounds__(256) k_gemm(
    const float* __restrict__ X, const float* __restrict__ W,
    const float* __restrict__ a_src, const float* __restrict__ a_dst,
    unsigned short* __restrict__ H16, float* __restrict__ S, float* __restrict__ Dv, int n) {
    __shared__ float Wl[FIN * 64];
    const int node0 = blockIdx.x * 64;
    constexpr int ROWF4 = FIN / 4;

    {
        const float4* W4 = (const float4*)W;
        float4* Wl4 = (float4*)Wl;
        for (int f = threadIdx.x; f < FIN * 16; f += 256) Wl4[f] = W4[f];
    }
    __syncthreads();

    const int wave = threadIdx.x >> 6, lane = threadIdx.x & 63;
    const int nbase = wave * 16;
    float acc[16];
    #pragma unroll
    for (int i = 0; i < 16; i++) acc[i] = 0.f;

    const float4* X4 = (const float4*)X;
    for (int kg = 0; kg < ROWF4; kg++) {
        float w0 = Wl[(kg * 4 + 0) * 64 + lane];
        float w1 = Wl[(kg * 4 + 1) * 64 + lane];
        float w2 = Wl[(kg * 4 + 2) * 64 + lane];
        float w3 = Wl[(kg * 4 + 3) * 64 + lane];
        #pragma unroll
        for (int i = 0; i < 16; i++) {
            int node = node0 + nbase + i;
            float4 xv = make_float4(0.f, 0.f, 0.f, 0.f);
            if (node < n) xv = X4[(size_t)node * ROWF4 + kg];  // uniform bcast load
            acc[i] = fmaf(xv.x, w0, acc[i]);
            acc[i] = fmaf(xv.y, w1, acc[i]);
            acc[i] = fmaf(xv.z, w2, acc[i]);
            acc[i] = fmaf(xv.w, w3, acc[i]);
        }
    }

    float asl = a_src[lane], adl = a_dst[lane];
    #pragma unroll
    for (int i = 0; i < 16; i++) {
        int node = node0 + nbase + i;
        if (node < n) {  // wave-uniform branch
            H16[(size_t)node * 64 + lane] = f2bf(acc[i]);
            float ps = wave_red_sum(acc[i] * asl);
            float pd = wave_red_sum(acc[i] * adl);
            if (lane == 0) { S[node] = ps; Dv[node] = pd; }
        }
    }
}

// ---------------- node-parallel GAT aggregate (bf16 H gather) ----------------
__global__ void __launch_bounds__(256) k_aggregate(
    const unsigned int* __restrict__ H2, const float* __restrict__ S,
    const float* __restrict__ Dv,
    const int* __restrict__ row_ptr, const int* __restrict__ csr_src,
    const float* __restrict__ bias, float* __restrict__ out, int n) {
    int wave = threadIdx.x >> 6, lane = threadIdx.x & 63;
    int node = blockIdx.x * 4 + wave;
    if (node >= n) return;
    int start = row_ptr[node], end = row_ptr[node + 1];
    float dn = Dv[node];
    int half = lane >> 5;
    int col = lane & 31;
    float accL0 = 0.f, accH0 = 0.f, accL1 = 0.f, accH1 = 0.f;
    float zlane = 0.f;
    for (int base = start; base < end; base += 64) {
        int cnt = min(64, end - base);
        int sj = 0;
        float w = 0.f;
        if (lane < cnt) {
            sj = csr_src[base + lane];
            float t = S[sj] + dn;
            t = (t > 0.f) ? t : NEG_SLOPE * t;
            w = __expf(t);
        }
        zlane += w;
        for (int jj = 0; jj < cnt; jj += 4) {
            int i0 = min(jj + half, 63);
            int i1 = min(jj + 2 + half, 63);
            float w0 = __shfl(w, i0);
            float w1 = __shfl(w, i1);
            int s0 = __shfl(sj, i0);
            int s1 = __shfl(sj, i1);
            unsigned int u0 = H2[(size_t)s0 * 32 + col];
            unsigned int u1 = H2[(size_t)s1 * 32 + col];
            float l0 = __uint_as_float(u0 << 16);
            float h0 = __uint_as_float(u0 & 0xFFFF0000u);
            float l1 = __uint_as_float(u1 << 16);
            float h1 = __uint_as_float(u1 & 0xFFFF0000u);
            accL0 = fmaf(w0, l0, accL0);
            accH0 = fmaf(w0, h0, accH0);
            accL1 = fmaf(w1, l1, accL1);
            accH1 = fmaf(w1, h1, accH1);
        }
    }
    float z = wave_red_sum(zlane);
    float accL = accL0 + accL1;
    float accH = accH0 + accH1;
    accL += __shfl_xor(accL, 32);
    accH += __shfl_xor(accH, 32);
    if (half == 0) {
        float2 b2 = ((const float2*)bias)[col];
        float2 o;
        o.x = accL / z + b2.x;
        o.y = accH / z + b2.y;
        ((float2*)out)[(size_t)node * 32 + col] = o;
    }
}

// ---------------- batchnorm ----------------
__global__ void k_zero_stats(float* stats) {
    if (threadIdx.x < 128) stats[threadIdx.x] = 0.f;
}

__global__ void __launch_bounds__(256) k_colstats(const float* __restrict__ T, int n,
                                                  float* __restrict__ sums,
                                                  float* __restrict__ sumsq) {
    __shared__ float ls[256], lq[256];
    int f = threadIdx.x & 63;
    int rowgrp = threadIdx.x >> 6;
    float s = 0.f, q = 0.f;
    for (int r = blockIdx.x * 4 + rowgrp; r < n; r += gridDim.x * 4) {
        float v = T[(size_t)r * 64 + f];
        s += v;
        q += v * v;
    }
    ls[threadIdx.x] = s; lq[threadIdx.x] = q;
    __syncthreads();
    if (threadIdx.x < 128) {
        ls[threadIdx.x] += ls[threadIdx.x + 128];
        lq[threadIdx.x] += lq[threadIdx.x + 128];
    }
    __syncthreads();
    if (threadIdx.x < 64) {
        atomicAdd(&sums[f], ls[threadIdx.x] + ls[threadIdx.x + 64]);
        atomicAdd(&sumsq[f], lq[threadIdx.x] + lq[threadIdx.x + 64]);
    }
}

__global__ void k_bn_finalize(const float* __restrict__ sums, const float* __restrict__ sumsq,
                              const float* __restrict__ g, const float* __restrict__ be,
                              int n, float* __restrict__ sc, float* __restrict__ sh) {
    int f = threadIdx.x;
    if (f < 64) {
        float inv_n = 1.f / (float)n;
        float mu = sums[f] * inv_n;
        float var = sumsq[f] * inv_n - mu * mu;
        float rstd = rsqrtf(var + BN_EPS);
        float scale = rstd * g[f];
        sc[f] = scale;
        sh[f] = be[f] - mu * scale;
    }
}

// in-place BN+ReLU on T [n][64], float4-vectorized
__global__ void __launch_bounds__(256) k_bn_apply(float* __restrict__ T,
                                                  const float* __restrict__ sc,
                                                  const float* __restrict__ sh, int n16) {
    int stride = gridDim.x * blockDim.x;
    float4* T4 = (float4*)T;
    for (int i = blockIdx.x * blockDim.x + threadIdx.x; i < n16; i += stride) {
        int k = (i & 15) * 4;
        float4 v = T4[i];
        v.x = fmaxf(fmaf(v.x, sc[k + 0], sh[k + 0]), 0.f);
        v.y = fmaxf(fmaf(v.y, sc[k + 1], sh[k + 1]), 0.f);
        v.z = fmaxf(fmaf(v.z, sc[k + 2], sh[k + 2]), 0.f);
        v.w = fmaxf(fmaf(v.w, sc[k + 3], sh[k + 3]), 0.f);
        T4[i] = v;
    }
}

extern "C" void kernel_launch(void* const* d_in, const int* in_sizes, int n_in,
                              void* d_out, int out_size, void* d_ws, size_t ws_size,
                              hipStream_t stream) {
    const float* x        = (const float*)d_in[0];
    const int*   ei       = (const int*)d_in[1];
    const float* W_in     = (const float*)d_in[2];
    const float* a_src_in = (const float*)d_in[3];
    const float* a_dst_in = (const float*)d_in[4];
    const float* b_in     = (const float*)d_in[5];
    const float* W_mid    = (const float*)d_in[6];
    const float* a_src_mid= (const float*)d_in[7];
    const float* a_dst_mid= (const float*)d_in[8];
    const float* b_mid    = (const float*)d_in[9];
    const float* gamma    = (const float*)d_in[10];
    const float* beta     = (const float*)d_in[11];
    const float* W_out    = (const float*)d_in[12];
    const float* a_src_out= (const float*)d_in[13];
    const float* a_dst_out= (const float*)d_in[14];
    const float* b_out    = (const float*)d_in[15];

    int n = in_sizes[0] / 128;   // 50000
    int E = in_sizes[1] / 2;     // 1250000
    const int* srcE = ei;
    const int* dstE = ei + E;
    int NB = (n + BSIZE - 1) >> BSHIFT;   // 391 (<= NBMAX assumed)

    auto alignup = [](size_t v) { return (v + 255) & ~(size_t)255; };
    char* p = (char*)d_ws;
    int* bcnt    = (int*)p; p += alignup(NBMAX * 4);
    int* bstart  = (int*)p; p += alignup((NBMAX + 1) * 4);
    int* gcursor = (int*)p; p += alignup(NBMAX * 4);
    int* row_ptr = (int*)p; p += alignup((size_t)(n + 1) * 4);
    int2* binned = (int2*)p; p += alignup((size_t)E * 8);
    int* csr     = (int*)p; p += alignup((size_t)(E + n) * 4);
    unsigned int* H2 = (unsigned int*)p; p += alignup((size_t)n * 32 * 4);  // bf16 [n][64]
    float* S     = (float*)p; p += alignup((size_t)n * 4);
    float* Dv    = (float*)p; p += alignup((size_t)n * 4);
    float* stats = (float*)p; p += alignup(128 * 4);
    float* bnsc  = (float*)p; p += alignup(64 * 4);
    float* bnsh  = (float*)p; p += alignup(64 * 4);
    float* T     = (float*)d_out;  // layer ping buffer; final aggregate rewrites it
    unsigned short* H16 = (unsigned short*)H2;

    // ---- binned CSR build (edges identical across all 5 layers) ----
    k_zero<<<(NBMAX + 255) / 256, 256, 0, stream>>>(bcnt, NBMAX);
    k_bucket_count<<<256, 256, 0, stream>>>(dstE, E / 4, bcnt);
    k_bucket_scan<<<1, 256, 0, stream>>>(bcnt, NB, bstart, gcursor);
    k_bin<<<(E + BIN_CHUNK - 1) / BIN_CHUNK, 256, 0, stream>>>(srcE, dstE, E, gcursor, binned);
    k_bucket_csr<<<NB, 256, 0, stream>>>(binned, bstart, n, NB, row_ptr, csr);

    int gb = (n + 3) / 4;        // aggregate grid (4 nodes/block)
    int gg = (n + 63) / 64;      // gemm grid (64 nodes/block)

    // ---- input GAT layer ----
    k_gemm<128><<<gg, 256, 0, stream>>>(x, W_in, a_src_in, a_dst_in, H16, S, Dv, n);
    k_aggregate<<<gb, 256, 0, stream>>>(H2, S, Dv, row_ptr, csr, b_in, T, n);

    // ---- mid layers: gat -> BN stats -> in-place BN+ReLU on T ----
    for (int l = 0; l < 3; l++) {
        k_gemm<64><<<gg, 256, 0, stream>>>(T, W_mid + l * 4096, a_src_mid + l * 64,
                                           a_dst_mid + l * 64, H16, S, Dv, n);
        k_aggregate<<<gb, 256, 0, stream>>>(H2, S, Dv, row_ptr, csr, b_mid + l * 64, T, n);
        k_zero_stats<<<1, 128, 0, stream>>>(stats);
        k_colstats<<<512, 256, 0, stream>>>(T, n, stats, stats + 64);
        k_bn_finalize<<<1, 64, 0, stream>>>(stats, stats + 64, gamma + l * 64, beta + l * 64,
                                            n, bnsc, bnsh);
        k_bn_apply<<<1024, 256, 0, stream>>>(T, bnsc, bnsh, n * 16);
    }

    // ---- output GAT layer ----
    k_gemm<64><<<gg, 256, 0, stream>>>(T, W_out, a_src_out, a_dst_out, H16, S, Dv, n);
    k_aggregate<<<gb, 256, 0, stream>>>(H2, S, Dv, row_ptr, csr, b_out, (float*)d_out, n);
}

// Round 10
// 368.724 us; speedup vs baseline: 3.6173x; 1.5289x over previous
//
#include <hip/hip_runtime.h>
#include <math.h>

#define NEG_SLOPE 0.2f
#define BN_EPS 1e-5f
#define BSHIFT 7
#define BSIZE 128          // nodes per bucket
#define NBMAX 512          // max buckets supported (n <= 65536)
#define BIN_CHUNK 8192

typedef short v8s __attribute__((ext_vector_type(8)));   // 8 bf16 (4 VGPRs)
typedef float v4f __attribute__((ext_vector_type(4)));   // 4 fp32 acc

static __device__ __forceinline__ float wave_red_sum(float v) {
    for (int off = 32; off; off >>= 1) v += __shfl_xor(v, off);
    return v;
}

// fp32 -> bf16 bits, round-to-nearest-even
static __device__ __forceinline__ unsigned short f2bf(float f) {
    unsigned int u = __float_as_uint(f);
    unsigned int r = u + 0x7FFFu + ((u >> 16) & 1u);
    return (unsigned short)(r >> 16);
}

static __device__ __forceinline__ float bf2f(unsigned short b) {
    return __uint_as_float(((unsigned int)b) << 16);
}

// hi/lo bf16 split: x ~= hi + lo, |err| ~ 2^-16 relative
static __device__ __forceinline__ void bfsplit(float x, unsigned short& h, unsigned short& l) {
    h = f2bf(x);
    l = f2bf(x - bf2f(h));
}

// ---------------- binned CSR build ----------------
__global__ void k_zero(int* p, int m) {
    int i = blockIdx.x * blockDim.x + threadIdx.x;
    if (i < m) p[i] = 0;
}

__global__ void __launch_bounds__(256) k_bucket_count(const int* __restrict__ dst, int E4,
                                                      int* __restrict__ bcnt) {
    __shared__ int lc[NBMAX];
    for (int i = threadIdx.x; i < NBMAX; i += 256) lc[i] = 0;
    __syncthreads();
    const int4* d4 = (const int4*)dst;
    int stride = gridDim.x * blockDim.x;
    for (int i = blockIdx.x * blockDim.x + threadIdx.x; i < E4; i += stride) {
        int4 v = d4[i];
        atomicAdd(&lc[v.x >> BSHIFT], 1);
        atomicAdd(&lc[v.y >> BSHIFT], 1);
        atomicAdd(&lc[v.z >> BSHIFT], 1);
        atomicAdd(&lc[v.w >> BSHIFT], 1);
    }
    __syncthreads();
    for (int i = threadIdx.x; i < NBMAX; i += 256)
        if (lc[i] > 0) atomicAdd(&bcnt[i], lc[i]);
}

__global__ void __launch_bounds__(256) k_bucket_scan(const int* __restrict__ bcnt, int NB,
                                                     int* __restrict__ bstart,
                                                     int* __restrict__ gcursor) {
    __shared__ int wsum[256];
    int tid = threadIdx.x;
    int i0 = tid * 2, i1 = tid * 2 + 1;
    int v0 = bcnt[i0], v1 = bcnt[i1];
    int s = v0 + v1;
    wsum[tid] = s;
    __syncthreads();
    for (int off = 1; off < 256; off <<= 1) {
        int t = (tid >= off) ? wsum[tid - off] : 0;
        __syncthreads();
        wsum[tid] += t;
        __syncthreads();
    }
    int excl = wsum[tid] - s;
    if (i0 < NB) { bstart[i0] = excl; gcursor[i0] = excl; }
    excl += v0;
    if (i1 < NB) { bstart[i1] = excl; gcursor[i1] = excl; }
    if (tid == 255) bstart[NB] = wsum[255];
}

__global__ void __launch_bounds__(256) k_bin(const int* __restrict__ src,
                                             const int* __restrict__ dst, int E,
                                             int* __restrict__ gcursor,
                                             int2* __restrict__ binned) {
    __shared__ int lc[NBMAX], lbase[NBMAX];
    int e0 = blockIdx.x * BIN_CHUNK;
    int e1 = min(e0 + BIN_CHUNK, E);
    for (int i = threadIdx.x; i < NBMAX; i += 256) lc[i] = 0;
    __syncthreads();
    for (int i = e0 + threadIdx.x; i < e1; i += 256)
        atomicAdd(&lc[dst[i] >> BSHIFT], 1);
    __syncthreads();
    for (int i = threadIdx.x; i < NBMAX; i += 256) {
        int c = lc[i];
        if (c > 0) lbase[i] = atomicAdd(&gcursor[i], c);
    }
    __syncthreads();
    for (int i = threadIdx.x; i < NBMAX; i += 256) lc[i] = 0;
    __syncthreads();
    for (int i = e0 + threadIdx.x; i < e1; i += 256) {
        int d = dst[i];
        int b = d >> BSHIFT;
        int pos = lbase[b] + atomicAdd(&lc[b], 1);
        binned[pos] = make_int2(src[i], d);
    }
}

__global__ void __launch_bounds__(256) k_bucket_csr(
    const int2* __restrict__ binned, const int* __restrict__ bstart, int n, int NB,
    int* __restrict__ row_ptr, int* __restrict__ csr_src) {
    __shared__ int cnt[BSIZE];
    __shared__ int wsum[BSIZE];
    int b = blockIdx.x;
    int node0 = b << BSHIFT;
    int nnodes = min(BSIZE, n - node0);
    int tid = threadIdx.x;
    if (tid < BSIZE) cnt[tid] = (tid < nnodes) ? 1 : 0;  // self loop
    __syncthreads();
    int ebeg = bstart[b], eend = bstart[b + 1];
    for (int i = ebeg + tid; i < eend; i += 256)
        atomicAdd(&cnt[binned[i].y & (BSIZE - 1)], 1);
    __syncthreads();
    int c = 0;
    if (tid < BSIZE) { c = cnt[tid]; wsum[tid] = c; }
    __syncthreads();
    for (int off = 1; off < BSIZE; off <<= 1) {
        int t = (tid >= off && tid < BSIZE) ? wsum[tid - off] : 0;
        __syncthreads();
        if (tid < BSIZE) wsum[tid] += t;
        __syncthreads();
    }
    int csr_base = ebeg + node0;
    if (tid < BSIZE) {
        int excl = wsum[tid] - c;
        int node = node0 + tid;
        if (tid < nnodes) {
            row_ptr[node] = csr_base + excl;
            csr_src[csr_base + excl] = node;  // self loop first
        }
        cnt[tid] = excl + 1;
    }
    if (b == NB - 1 && tid == BSIZE - 1) row_ptr[n] = csr_base + wsum[BSIZE - 1];
    __syncthreads();
    for (int i = ebeg + tid; i < eend; i += 256) {
        int2 e2 = binned[i];
        int pos = csr_base + atomicAdd(&cnt[e2.y & (BSIZE - 1)], 1);
        csr_src[pos] = e2.x;
    }
}

// ---------------- MFMA per-layer GEMM (bf16x3, fp32-quality): H(bf16)=act(X)@W ----
// Block = 64 nodes, 4 waves; wave = 16 nodes x 64 feats = 4 mfma_f32_16x16x32_bf16
// fragments per k-chunk. X and W^T staged as bf16 HI/LO pairs (x ~= hi+lo), each
// XOR-swizzled (byte ^= (row&7)<<4). acc += Ah*Bh + Ah*Bl + Al*Bh  -> ~fp32
// precision (lo*lo ~2^-32 dropped). Layouts (m89): A row=lane&15, k=8*(lane>>4)+e;
// B col=lane&15, same k; D col=lane&15, row=4*(lane>>4)+reg.
template <int FIN, int USE_BN>
__global__ void __launch_bounds__(256) k_gemm(
    const float* __restrict__ X, const float* __restrict__ W,
    const float* __restrict__ a_src, const float* __restrict__ a_dst,
    const float* __restrict__ bn_sc, const float* __restrict__ bn_sh,
    unsigned short* __restrict__ H16, float* __restrict__ S, float* __restrict__ Dv, int n) {
    constexpr int RS = FIN * 2;                  // row stride (bytes) per tile
    constexpr int NF4 = FIN / 4;                 // float4 per X row
    __shared__ unsigned int Xh[64 * FIN / 2];    // bf16 hi [64 nodes][FIN], swizzled
    __shared__ unsigned int Xo[64 * FIN / 2];    // bf16 lo
    __shared__ unsigned int Wh[64 * FIN / 2];    // bf16 hi W^T [64 feat][FIN k]
    __shared__ unsigned int Wo[64 * FIN / 2];    // bf16 lo
    const int t = threadIdx.x;
    const int node0 = blockIdx.x * 64;

    // ---- stage X (+BN+ReLU) -> hi/lo bf16, swizzled ----
    const float4* X4 = (const float4*)X;
    for (int idx = t; idx < 64 * NF4; idx += 256) {
        int r = idx / NF4, c4 = idx % NF4;
        float4 v = make_float4(0.f, 0.f, 0.f, 0.f);
        if (node0 + r < n) v = X4[(size_t)(node0 + r) * NF4 + c4];
        if (USE_BN) {
            int k = c4 * 4;
            v.x = fmaxf(fmaf(v.x, bn_sc[k + 0], bn_sh[k + 0]), 0.f);
            v.y = fmaxf(fmaf(v.y, bn_sc[k + 1], bn_sh[k + 1]), 0.f);
            v.z = fmaxf(fmaf(v.z, bn_sc[k + 2], bn_sh[k + 2]), 0.f);
            v.w = fmaxf(fmaf(v.w, bn_sc[k + 3], bn_sh[k + 3]), 0.f);
        }
        unsigned short hx, lx, hy, ly, hz, lz, hw, lw;
        bfsplit(v.x, hx, lx); bfsplit(v.y, hy, ly);
        bfsplit(v.z, hz, lz); bfsplit(v.w, hw, lw);
        int byte = r * RS + c4 * 8;
        int sw = (byte ^ ((r & 7) << 4)) >> 2;
        Xh[sw + 0] = (unsigned int)hx | ((unsigned int)hy << 16);
        Xh[sw + 1] = (unsigned int)hz | ((unsigned int)hw << 16);
        Xo[sw + 0] = (unsigned int)lx | ((unsigned int)ly << 16);
        Xo[sw + 1] = (unsigned int)lz | ((unsigned int)lw << 16);
    }
    // ---- stage W^T -> hi/lo bf16, swizzled (W global is [FIN k][64 feat]) ----
    for (int idx = t; idx < FIN * 32; idx += 256) {
        int feat = idx & 63;
        int k2 = (idx >> 6) * 2;
        float w0 = W[(size_t)k2 * 64 + feat];
        float w1 = W[(size_t)(k2 + 1) * 64 + feat];
        unsigned short h0, l0, h1, l1;
        bfsplit(w0, h0, l0); bfsplit(w1, h1, l1);
        int byte = feat * RS + k2 * 2;
        int sw = (byte ^ ((feat & 7) << 4)) >> 2;
        Wh[sw] = (unsigned int)h0 | ((unsigned int)h1 << 16);
        Wo[sw] = (unsigned int)l0 | ((unsigned int)l1 << 16);
    }
    __syncthreads();

    const int wave = t >> 6, lane = t & 63;
    const int g = lane >> 4, li = lane & 15;
    const int nbase = wave * 16;

    v4f acc[4];
    #pragma unroll
    for (int f = 0; f < 4; f++) acc[f] = (v4f){0.f, 0.f, 0.f, 0.f};

    const int rowA = nbase + li;
    #pragma unroll
    for (int kc = 0; kc < FIN / 32; kc++) {
        int offA = (rowA * RS + kc * 64 + g * 16) ^ ((rowA & 7) << 4);
        v8s ah = *(const v8s*)((const char*)Xh + offA);
        v8s al = *(const v8s*)((const char*)Xo + offA);
        #pragma unroll
        for (int f = 0; f < 4; f++) {
            int rowW = f * 16 + li;
            int offB = (rowW * RS + kc * 64 + g * 16) ^ ((rowW & 7) << 4);
            v8s bh = *(const v8s*)((const char*)Wh + offB);
            v8s bl = *(const v8s*)((const char*)Wo + offB);
            acc[f] = __builtin_amdgcn_mfma_f32_16x16x32_bf16(ah, bh, acc[f], 0, 0, 0);
            acc[f] = __builtin_amdgcn_mfma_f32_16x16x32_bf16(ah, bl, acc[f], 0, 0, 0);
            acc[f] = __builtin_amdgcn_mfma_f32_16x16x32_bf16(al, bh, acc[f], 0, 0, 0);
        }
    }

    // ---- epilogue: H bf16 stores + per-node score dots (16-lane group reduce) ----
    float as_[4], ad_[4];
    #pragma unroll
    for (int f = 0; f < 4; f++) { as_[f] = a_src[f * 16 + li]; ad_[f] = a_dst[f * 16 + li]; }
    #pragma unroll
    for (int j = 0; j < 4; j++) {
        int node = node0 + nbase + g * 4 + j;
        float ps = acc[0][j] * as_[0] + acc[1][j] * as_[1] +
                   acc[2][j] * as_[2] + acc[3][j] * as_[3];
        float pd = acc[0][j] * ad_[0] + acc[1][j] * ad_[1] +
                   acc[2][j] * ad_[2] + acc[3][j] * ad_[3];
        #pragma unroll
        for (int m = 1; m < 16; m <<= 1) {
            ps += __shfl_xor(ps, m);
            pd += __shfl_xor(pd, m);
        }
        if (node < n) {
            #pragma unroll
            for (int f = 0; f < 4; f++)
                H16[(size_t)node * 64 + f * 16 + li] = f2bf(acc[f][j]);
            if (li == 0) { S[node] = ps; Dv[node] = pd; }
        }
    }
}

// ---------------- node-parallel GAT aggregate (bf16 H gather) ----------------
__global__ void __launch_bounds__(256) k_aggregate(
    const unsigned int* __restrict__ H2, const float* __restrict__ S,
    const float* __restrict__ Dv,
    const int* __restrict__ row_ptr, const int* __restrict__ csr_src,
    const float* __restrict__ bias, float* __restrict__ out, int n) {
    int wave = threadIdx.x >> 6, lane = threadIdx.x & 63;
    int node = blockIdx.x * 4 + wave;
    if (node >= n) return;
    int start = row_ptr[node], end = row_ptr[node + 1];
    float dn = Dv[node];
    int half = lane >> 5;
    int col = lane & 31;
    float accL0 = 0.f, accH0 = 0.f, accL1 = 0.f, accH1 = 0.f;
    float zlane = 0.f;
    for (int base = start; base < end; base += 64) {
        int cnt = min(64, end - base);
        int sj = 0;
        float w = 0.f;
        if (lane < cnt) {
            sj = csr_src[base + lane];
            float t = S[sj] + dn;
            t = (t > 0.f) ? t : NEG_SLOPE * t;
            w = __expf(t);
        }
        zlane += w;
        for (int jj = 0; jj < cnt; jj += 4) {
            int i0 = min(jj + half, 63);
            int i1 = min(jj + 2 + half, 63);
            float w0 = __shfl(w, i0);
            float w1 = __shfl(w, i1);
            int s0 = __shfl(sj, i0);
            int s1 = __shfl(sj, i1);
            unsigned int u0 = H2[(size_t)s0 * 32 + col];
            unsigned int u1 = H2[(size_t)s1 * 32 + col];
            float l0 = __uint_as_float(u0 << 16);
            float h0 = __uint_as_float(u0 & 0xFFFF0000u);
            float l1 = __uint_as_float(u1 << 16);
            float h1 = __uint_as_float(u1 & 0xFFFF0000u);
            accL0 = fmaf(w0, l0, accL0);
            accH0 = fmaf(w0, h0, accH0);
            accL1 = fmaf(w1, l1, accL1);
            accH1 = fmaf(w1, h1, accH1);
        }
    }
    float z = wave_red_sum(zlane);
    float accL = accL0 + accL1;
    float accH = accH0 + accH1;
    accL += __shfl_xor(accL, 32);
    accH += __shfl_xor(accH, 32);
    if (half == 0) {
        float2 b2 = ((const float2*)bias)[col];
        float2 o;
        o.x = accL / z + b2.x;
        o.y = accH / z + b2.y;
        ((float2*)out)[(size_t)node * 32 + col] = o;
    }
}

// ---------------- batchnorm stats ----------------
__global__ void k_zero_stats(float* stats) {
    if (threadIdx.x < 128) stats[threadIdx.x] = 0.f;
}

__global__ void __launch_bounds__(256) k_colstats(const float* __restrict__ T, int n,
                                                  float* __restrict__ sums,
                                                  float* __restrict__ sumsq) {
    __shared__ float ls[256], lq[256];
    int f = threadIdx.x & 63;
    int rowgrp = threadIdx.x >> 6;
    float s = 0.f, q = 0.f;
    for (int r = blockIdx.x * 4 + rowgrp; r < n; r += gridDim.x * 4) {
        float v = T[(size_t)r * 64 + f];
        s += v;
        q += v * v;
    }
    ls[threadIdx.x] = s; lq[threadIdx.x] = q;
    __syncthreads();
    if (threadIdx.x < 128) {
        ls[threadIdx.x] += ls[threadIdx.x + 128];
        lq[threadIdx.x] += lq[threadIdx.x + 128];
    }
    __syncthreads();
    if (threadIdx.x < 64) {
        atomicAdd(&sums[f], ls[threadIdx.x] + ls[threadIdx.x + 64]);
        atomicAdd(&sumsq[f], lq[threadIdx.x] + lq[threadIdx.x + 64]);
    }
}

__global__ void k_bn_finalize(const float* __restrict__ sums, const float* __restrict__ sumsq,
                              const float* __restrict__ g, const float* __restrict__ be,
                              int n, float* __restrict__ sc, float* __restrict__ sh) {
    int f = threadIdx.x;
    if (f < 64) {
        float inv_n = 1.f / (float)n;
        float mu = sums[f] * inv_n;
        float var = sumsq[f] * inv_n - mu * mu;
        float rstd = rsqrtf(var + BN_EPS);
        float scale = rstd * g[f];
        sc[f] = scale;
        sh[f] = be[f] - mu * scale;
    }
}

extern "C" void kernel_launch(void* const* d_in, const int* in_sizes, int n_in,
                              void* d_out, int out_size, void* d_ws, size_t ws_size,
                              hipStream_t stream) {
    const float* x        = (const float*)d_in[0];
    const int*   ei       = (const int*)d_in[1];
    const float* W_in     = (const float*)d_in[2];
    const float* a_src_in = (const float*)d_in[3];
    const float* a_dst_in = (const float*)d_in[4];
    const float* b_in     = (const float*)d_in[5];
    const float* W_mid    = (const float*)d_in[6];
    const float* a_src_mid= (const float*)d_in[7];
    const float* a_dst_mid= (const float*)d_in[8];
    const float* b_mid    = (const float*)d_in[9];
    const float* gamma    = (const float*)d_in[10];
    const float* beta     = (const float*)d_in[11];
    const float* W_out    = (const float*)d_in[12];
    const float* a_src_out= (const float*)d_in[13];
    const float* a_dst_out= (const float*)d_in[14];
    const float* b_out    = (const float*)d_in[15];

    int n = in_sizes[0] / 128;   // 50000
    int E = in_sizes[1] / 2;     // 1250000
    const int* srcE = ei;
    const int* dstE = ei + E;
    int NB = (n + BSIZE - 1) >> BSHIFT;   // 391 (<= NBMAX assumed)

    auto alignup = [](size_t v) { return (v + 255) & ~(size_t)255; };
    char* p = (char*)d_ws;
    int* bcnt    = (int*)p; p += alignup(NBMAX * 4);
    int* bstart  = (int*)p; p += alignup((NBMAX + 1) * 4);
    int* gcursor = (int*)p; p += alignup(NBMAX * 4);
    int* row_ptr = (int*)p; p += alignup((size_t)(n + 1) * 4);
    int2* binned = (int2*)p; p += alignup((size_t)E * 8);
    int* csr     = (int*)p; p += alignup((size_t)(E + n) * 4);
    unsigned int* H2 = (unsigned int*)p; p += alignup((size_t)n * 32 * 4);  // bf16 [n][64]
    float* S     = (float*)p; p += alignup((size_t)n * 4);
    float* Dv    = (float*)p; p += alignup((size_t)n * 4);
    float* stats = (float*)p; p += alignup(128 * 4);
    float* bnsc  = (float*)p; p += alignup(64 * 4);
    float* bnsh  = (float*)p; p += alignup(64 * 4);
    float* T     = (float*)d_out;  // layer ping buffer; final aggregate rewrites it
    unsigned short* H16 = (unsigned short*)H2;

    // ---- binned CSR build (edges identical across all 5 layers) ----
    k_zero<<<(NBMAX + 255) / 256, 256, 0, stream>>>(bcnt, NBMAX);
    k_bucket_count<<<256, 256, 0, stream>>>(dstE, E / 4, bcnt);
    k_bucket_scan<<<1, 256, 0, stream>>>(bcnt, NB, bstart, gcursor);
    k_bin<<<(E + BIN_CHUNK - 1) / BIN_CHUNK, 256, 0, stream>>>(srcE, dstE, E, gcursor, binned);
    k_bucket_csr<<<NB, 256, 0, stream>>>(binned, bstart, n, NB, row_ptr, csr);

    int gb = (n + 3) / 4;        // aggregate grid (4 nodes/block)
    int gg = (n + 63) / 64;      // gemm grid (64 nodes/block)

    // ---- input GAT layer ----
    k_gemm<128, 0><<<gg, 256, 0, stream>>>(x, W_in, a_src_in, a_dst_in, nullptr, nullptr,
                                           H16, S, Dv, n);
    k_aggregate<<<gb, 256, 0, stream>>>(H2, S, Dv, row_ptr, csr, b_in, T, n);

    // ---- mid layers: gat -> BN stats; BN+ReLU fused into next gemm's X staging ----
    for (int l = 0; l < 3; l++) {
        if (l == 0)
            k_gemm<64, 0><<<gg, 256, 0, stream>>>(T, W_mid + l * 4096, a_src_mid + l * 64,
                                                  a_dst_mid + l * 64, nullptr, nullptr,
                                                  H16, S, Dv, n);
        else
            k_gemm<64, 1><<<gg, 256, 0, stream>>>(T, W_mid + l * 4096, a_src_mid + l * 64,
                                                  a_dst_mid + l * 64, bnsc, bnsh,
                                                  H16, S, Dv, n);
        k_aggregate<<<gb, 256, 0, stream>>>(H2, S, Dv, row_ptr, csr, b_mid + l * 64, T, n);
        k_zero_stats<<<1, 128, 0, stream>>>(stats);
        k_colstats<<<512, 256, 0, stream>>>(T, n, stats, stats + 64);
        k_bn_finalize<<<1, 64, 0, stream>>>(stats, stats + 64, gamma + l * 64, beta + l * 64,
                                            n, bnsc, bnsh);
    }

    // ---- output GAT layer (consumes BN+ReLU of last mid layer) ----
    k_gemm<64, 1><<<gg, 256, 0, stream>>>(T, W_out, a_src_out, a_dst_out, bnsc, bnsh,
                                          H16, S, Dv, n);
    k_aggregate<<<gb, 256, 0, stream>>>(H2, S, Dv, row_ptr, csr, b_out, (float*)d_out, n);
}